// Round 6
// baseline (566.151 us; speedup 1.0000x reference)
//
#include <hip/hip_runtime.h>
#include <math.h>

// B=2,S=2048 -> NT=4096 tokens; K=8, D=1024, P=32, KP=4, DFF=4096
typedef unsigned short ushort_t;
typedef __attribute__((ext_vector_type(8))) short short8;
typedef __attribute__((ext_vector_type(4))) float floatx4;

static __device__ __forceinline__ ushort_t f2bf(float f){
  unsigned int u = __float_as_uint(f);
  unsigned int r = u + 0x7FFFu + ((u >> 16) & 1u);   // round-to-nearest-even
  return (ushort_t)(r >> 16);
}
static __device__ __forceinline__ void unpack8(uint4 u, float* f){
  f[0] = __uint_as_float(u.x << 16); f[1] = __uint_as_float(u.x & 0xffff0000u);
  f[2] = __uint_as_float(u.y << 16); f[3] = __uint_as_float(u.y & 0xffff0000u);
  f[4] = __uint_as_float(u.z << 16); f[5] = __uint_as_float(u.z & 0xffff0000u);
  f[6] = __uint_as_float(u.w << 16); f[7] = __uint_as_float(u.w & 0xffff0000u);
}
static __device__ __forceinline__ uint4 pack8(const float* f){
  uint4 u;
  u.x = (unsigned)f2bf(f[0]) | ((unsigned)f2bf(f[1]) << 16);
  u.y = (unsigned)f2bf(f[2]) | ((unsigned)f2bf(f[3]) << 16);
  u.z = (unsigned)f2bf(f[4]) | ((unsigned)f2bf(f[5]) << 16);
  u.w = (unsigned)f2bf(f[6]) | ((unsigned)f2bf(f[7]) << 16);
  return u;
}

static __device__ __forceinline__ void gload16(const void* g, void* l){
  __builtin_amdgcn_global_load_lds((const __attribute__((address_space(1))) void*)g,
                                   (__attribute__((address_space(3))) void*)l, 16, 0, 0);
}

// gelu(x) ~= x * sigmoid(1.5957691216 x + 0.0713548162 x^3)  (tanh form, hw exp)
static __device__ __forceinline__ float gelu_f(float v){
  float w = v * (-1.5957691216f - 0.0713548162f * v * v);
  return v / (1.0f + __expf(w));
}

// ------------- merged fp32 -> bf16 converts (6 tensors, one launch) ----------
__global__ __launch_bounds__(256) void k_cvt_multi(
    const float* __restrict__ s0, ushort_t* __restrict__ d0, int e0,
    const float* __restrict__ s1, ushort_t* __restrict__ d1, int e1,
    const float* __restrict__ s2, ushort_t* __restrict__ d2, int e2,
    const float* __restrict__ s3, ushort_t* __restrict__ d3, int e3,
    const float* __restrict__ s4, ushort_t* __restrict__ d4, int e4,
    const float* __restrict__ s5, ushort_t* __restrict__ d5, int e5){
  int i = blockIdx.x * 256 + threadIdx.x;
  const float* s; ushort_t* d; int b;
  if      (i < e0){ s = s0; d = d0; b = 0;  }
  else if (i < e1){ s = s1; d = d1; b = e0; }
  else if (i < e2){ s = s2; d = d2; b = e1; }
  else if (i < e3){ s = s3; d = d3; b = e2; }
  else if (i < e4){ s = s4; d = d4; b = e3; }
  else if (i < e5){ s = s5; d = d5; b = e4; }
  else return;
  int j = i - b;
  float4 v = ((const float4*)s)[j];
  unsigned long long p = (unsigned long long)f2bf(v.x)
                       | ((unsigned long long)f2bf(v.y) << 16)
                       | ((unsigned long long)f2bf(v.z) << 32)
                       | ((unsigned long long)f2bf(v.w) << 48);
  ((unsigned long long*)d)[j] = p;
}

// ---------------- 3x 1024x1024 transpose with bf16 convert (one launch) -------
__global__ __launch_bounds__(256) void k_transpose3(const float* __restrict__ s0, ushort_t* __restrict__ d0,
                                                    const float* __restrict__ s1, ushort_t* __restrict__ d1,
                                                    const float* __restrict__ s2, ushort_t* __restrict__ d2){
  __shared__ float tile[32][33];
  const float* in; ushort_t* out;
  if      (blockIdx.z == 0){ in = s0; out = d0; }
  else if (blockIdx.z == 1){ in = s1; out = d1; }
  else                     { in = s2; out = d2; }
  int bx = blockIdx.x * 32, by = blockIdx.y * 32;
  int tx = threadIdx.x & 31, ty = threadIdx.x >> 5;   // ty 0..7
  for (int i = 0; i < 32; i += 8)
    tile[ty + i][tx] = in[(size_t)(by + ty + i) * 1024 + bx + tx];
  __syncthreads();
  for (int i = 0; i < 32; i += 8)
    out[(size_t)(bx + ty + i) * 1024 + by + tx] = f2bf(tile[tx][ty + i]);
}

// -------- merged prep: wvec (256) | pb (8) | PV (256) | CB n32-GEMM (32) ------
__global__ __launch_bounds__(256) void k_prep(const float* __restrict__ bq,
                                              const ushort_t* __restrict__ WKT,
                                              float* __restrict__ wv,
                                              const float* __restrict__ pat,
                                              const float* __restrict__ bv,
                                              float* __restrict__ pb,
                                              const ushort_t* __restrict__ WVT,
                                              const ushort_t* __restrict__ PATB,
                                              ushort_t* __restrict__ PVB,
                                              const ushort_t* __restrict__ CTXB,
                                              float* __restrict__ CBb){
  __shared__ ushort_t As[128 * 32];
  __shared__ ushort_t Bs[32 * 32];
  const int bid = blockIdx.x;
  const int l = threadIdx.x & 63;
  if (bid < 256){            // wvec
    int d = (bid << 2) + (threadIdx.x >> 6);
    const uint4* row = (const uint4*)(WKT + (size_t)d * 1024 + (l << 4));
    const float4* b4 = (const float4*)(bq + (l << 4));
    float w[16], bb[16];
    unpack8(row[0], w); unpack8(row[1], w + 8);
#pragma unroll
    for (int i = 0; i < 4; i++){
      float4 v = b4[i];
      bb[i*4] = v.x; bb[i*4+1] = v.y; bb[i*4+2] = v.z; bb[i*4+3] = v.w;
    }
    float a = 0.f;
#pragma unroll
    for (int i = 0; i < 16; i++) a += w[i] * bb[i];
#pragma unroll
    for (int s = 1; s < 64; s <<= 1) a += __shfl_xor(a, s);
    if (l == 0) wv[d] = a;
  } else if (bid < 264){     // pb
    int p = ((bid - 256) << 2) + (threadIdx.x >> 6);
    const float4* pr = (const float4*)(pat + p * 1024) + l;
    const float4* b4 = (const float4*)bv + l;
    float a = 0.f;
#pragma unroll
    for (int i = 0; i < 4; i++){
      float4 x = pr[i * 64], y = b4[i * 64];
      a += x.x * y.x + x.y * y.y + x.z * y.z + x.w * y.w;
    }
#pragma unroll
    for (int s = 1; s < 64; s <<= 1) a += __shfl_xor(a, s);
    if (l == 0) pb[p] = a;
  } else if (bid < 520){     // PV
    int d = ((bid - 264) << 2) + (threadIdx.x >> 6);
    const uint4* wr = (const uint4*)(WVT + (size_t)d * 1024 + (l << 4));
    float w[16];
    unpack8(wr[0], w); unpack8(wr[1], w + 8);
    for (int p = 0; p < 32; p++){
      const uint4* pr = (const uint4*)(PATB + p * 1024 + (l << 4));
      float pw[16];
      unpack8(pr[0], pw); unpack8(pr[1], pw + 8);
      float a = 0.f;
#pragma unroll
      for (int i = 0; i < 16; i++) a += w[i] * pw[i];
#pragma unroll
      for (int s = 1; s < 64; s <<= 1) a += __shfl_xor(a, s);
      if (l == 0) PVB[p * 1024 + d] = f2bf(a);
    }
  } else {                   // CB[tok][p] = ctx_tok . pat_p  (n32 MFMA GEMM)
    const int tid = threadIdx.x;
    const int w = tid >> 6;
    const int m0 = (bid - 520) << 7;
    const int rA = (w << 4) + (l >> 2);
    const int cA = (l & 3) << 3;
    const int fr = l & 15, fq = l >> 4;
    const int K = 1024;
    floatx4 acc[2][2];
#pragma unroll
    for (int i = 0; i < 2; i++)
#pragma unroll
      for (int j = 0; j < 2; j++) acc[i][j] = (floatx4)0.0f;
    const ushort_t* Ab = CTXB + (size_t)(m0 + rA) * K + cA;
    const ushort_t* Bb = PATB + (size_t)rA * K + cA;
    const size_t row64 = (size_t)64 * K;
    for (int k0 = 0; k0 < K; k0 += 32){
      __syncthreads();
      gload16(Ab + k0, As + (w << 9));
      gload16(Ab + row64 + k0, As + 2048 + (w << 9));
      if (w < 2) gload16(Bb + k0, Bs + (w << 9));
      __syncthreads();
      short8 af[2], bg[2];
#pragma unroll
      for (int i = 0; i < 2; i++)
        af[i] = *(const short8*)(As + (((w << 5) + (i << 4) + fr) << 5) + (fq << 3));
#pragma unroll
      for (int j = 0; j < 2; j++)
        bg[j] = *(const short8*)(Bs + (((j << 4) + fr) << 5) + (fq << 3));
#pragma unroll
      for (int i = 0; i < 2; i++)
#pragma unroll
        for (int j = 0; j < 2; j++)
          acc[i][j] = __builtin_amdgcn_mfma_f32_16x16x32_bf16(af[i], bg[j], acc[i][j], 0, 0, 0);
    }
#pragma unroll
    for (int i = 0; i < 2; i++){
      int row = m0 + (w << 5) + (i << 4) + (fq << 2);
#pragma unroll
      for (int j = 0; j < 2; j++){
        int col = (j << 4) + fr;
#pragma unroll
        for (int r = 0; r < 4; r++)
          CBb[(size_t)(row + r) * 32 + col] = acc[i][j][r];
      }
    }
  }
}

// =============== 256x256-tile GEMM: 2-barrier counted-vmcnt K-loop ===========
// 512 threads = 8 waves (2M x 4N). BK=64. LDS 128 KiB dbuf.
// Per K-tile t: STG all 4 halves of t+1 (8 loads, ~1 K-tile of latency cover)
// -> vmcnt(8) (drains exactly the t-batch; wait-after-issue) -> barrier ->
// free-form reads+MFMAs (compiler interleaves via fine lgkmcnt -> LDS pipe
// overlaps MFMA pipe) -> barrier (protects dbuf overwrite next iter).
// LDS swizzle: byte ^= (row&7)<<4 as involution on both stage-src and read.
// MODE 1: bf16(acc+bias)  MODE 3: bf16(gelu(acc+bias))
#define SBAR_  __builtin_amdgcn_s_barrier()
#define SCHED_ __builtin_amdgcn_sched_barrier(0)
#define VM8_   asm volatile("s_waitcnt vmcnt(8)" ::: "memory")
#define VM0_   asm volatile("s_waitcnt vmcnt(0)" ::: "memory")

#define STG_(Gp, Lp, qh, tt) do{ \
    const ushort_t* _g = (Gp) + (size_t)(((qh) << 7) + (wid << 3)) * K + ((tt) << 6); \
    char* _l = (Lp) + ((((tt) & 1) << 15) | ((qh) << 14) | (wid << 10)); \
    gload16(_g, _l); \
    gload16(_g + ((size_t)K << 6), _l + 8192); \
  }while(0)

#define RDA_(qm, cb) do{ \
    _Pragma("unroll") \
    for (int _i = 0; _i < 4; _i++){ \
      af[_i][0] = *(const short8*)(AsB + (cb) + ((qm) << 14) + arow + (_i << 11) + c0); \
      af[_i][1] = *(const short8*)(AsB + (cb) + ((qm) << 14) + arow + (_i << 11) + c1); \
    } }while(0)

#define RDB_(qn, cb) do{ \
    _Pragma("unroll") \
    for (int _j = 0; _j < 2; _j++){ \
      bg[qn][_j][0] = *(const short8*)(BsB + (cb) + ((qn) << 14) + brow + (_j << 11) + c0); \
      bg[qn][_j][1] = *(const short8*)(BsB + (cb) + ((qn) << 14) + brow + (_j << 11) + c1); \
    } }while(0)

#define MFMA_(qm, qn) do{ \
    _Pragma("unroll") \
    for (int _i = 0; _i < 4; _i++) \
    _Pragma("unroll") \
      for (int _j = 0; _j < 2; _j++){ \
        acc[qm][_i][qn][_j] = __builtin_amdgcn_mfma_f32_16x16x32_bf16(af[_i][0], bg[qn][_j][0], acc[qm][_i][qn][_j], 0, 0, 0); \
        acc[qm][_i][qn][_j] = __builtin_amdgcn_mfma_f32_16x16x32_bf16(af[_i][1], bg[qn][_j][1], acc[qm][_i][qn][_j], 0, 0, 0); \
      } }while(0)

template<int MODE>
__global__ __launch_bounds__(512, 2) void k_gemm8(const ushort_t* __restrict__ A,
                                                  const ushort_t* __restrict__ B,
                                                  void* __restrict__ C,
                                                  const float* __restrict__ bias,
                                                  int N, int K, int ntn){
  __shared__ __align__(16) ushort_t As[2 * 256 * 64];   // 64 KB
  __shared__ __align__(16) ushort_t Bs[2 * 256 * 64];   // 64 KB
  const int tid = threadIdx.x;
  const int wid = tid >> 6, l = tid & 63;
  const int wr = wid >> 2, wc = wid & 3;
  const int fr = l & 15, fq = l >> 4;
  const int id = blockIdx.x;
  const int xcd = id & 7, t2 = id >> 3;
  const int nt = t2 % ntn, mq = t2 / ntn;
  const int mt = (mq << 3) + xcd;
  const int m0 = mt << 8, n0 = nt << 8;
  const int NT = K >> 6;

  // staging: lane l of chunk c loads global row c*8+(l>>3), 16B-block (l&7)^(l>>3)
  const int sgr = l >> 3;
  const int sgc = ((l & 7) ^ (l >> 3)) << 3;
  const ushort_t* Ag = A + (size_t)(m0 + sgr) * K + sgc;
  const ushort_t* Bg = B + (size_t)(n0 + sgr) * K + sgc;
  char* AsB = (char*)As;
  char* BsB = (char*)Bs;
  // ds_read: swizzled col16 = col16lin ^ (row&7); row&7 == fr&7 here
  const int c0 = ((fq ^ (fr & 7)) << 4);
  const int c1 = (((4 | fq) ^ (fr & 7)) << 4);
  const int arow = (wr << 13) + fr * 128;     // + qm*16384 + i*2048
  const int brow = (wc << 12) + fr * 128;     // + qn*16384 + j*2048

  floatx4 acc[2][4][2][2];
#pragma unroll
  for (int a = 0; a < 2; a++)
#pragma unroll
    for (int b = 0; b < 4; b++)
#pragma unroll
      for (int c = 0; c < 2; c++)
#pragma unroll
        for (int d = 0; d < 2; d++) acc[a][b][c][d] = (floatx4)0.0f;
  short8 af[4][2], bg[2][2][2];

  // prologue: stage tile 0 (8 loads/wave in flight)
  STG_(Ag, AsB, 0, 0);
  STG_(Bg, BsB, 0, 0);
  STG_(Bg, BsB, 1, 0);
  STG_(Ag, AsB, 1, 0);

  for (int t = 0; t < NT; t++){
    const int cur = (t & 1) << 15;
    const int tn = t + 1;
    if (tn < NT){
      // stage ALL of tile t+1 into the other buffer (safe: all waves passed
      // the trailing barrier of t-1, so reads of that buffer are done)
      STG_(Ag, AsB, 0, tn);
      STG_(Bg, BsB, 0, tn);
      STG_(Bg, BsB, 1, tn);
      STG_(Ag, AsB, 1, tn);
      VM8_;              // drains exactly the t-batch (8 newest stay in flight)
    } else {
      VM0_;              // last tile: drain everything
    }
    SBAR_; SCHED_;       // all waves' t-batch landed; fence reads below barrier
    RDA_(0, cur); RDB_(0, cur);
    MFMA_(0, 0);
    RDB_(1, cur);
    MFMA_(0, 1);
    RDA_(1, cur);
    MFMA_(1, 1);
    MFMA_(1, 0);
    SCHED_; SBAR_;       // all waves done reading buf[t&1] before next overwrite
  }

  // epilogue
#pragma unroll
  for (int qm = 0; qm < 2; qm++)
#pragma unroll
    for (int i = 0; i < 4; i++){
      const int row = m0 + (qm << 7) + (wr << 6) + (i << 4) + (fq << 2);
#pragma unroll
      for (int qn = 0; qn < 2; qn++)
#pragma unroll
        for (int j = 0; j < 2; j++){
          const int col = n0 + (qn << 7) + (wc << 5) + (j << 4) + fr;
          const float bsv = bias[col];
#pragma unroll
          for (int r = 0; r < 4; r++){
            float v = acc[qm][i][qn][j][r] + bsv;
            if (MODE == 3) v = gelu_f(v);
            ((ushort_t*)C)[(size_t)(row + r) * N + col] = f2bf(v);
          }
        }
    }
}

// ---------- 64x128-tile GEMM, BK=64 double-stage (small-M shapes) ------------
// Per-XCD enumeration nt-outer -> B-tile L2-resident across the mq sweep.
// MODE 0: bf16(acc) 2: bf16(acc+bias+Xadd) 4: fp32(acc+bias)
template<int MODE, int GN>
__global__ __launch_bounds__(256) void k_gemm_bt64(const ushort_t* __restrict__ A,
                                                   const ushort_t* __restrict__ B,
                                                   void* __restrict__ C,
                                                   const float* __restrict__ bias,
                                                   const float* __restrict__ Xadd,
                                                   int N, int K){
  __shared__ ushort_t As[2 * 64 * 32];    // 8 KB
  __shared__ ushort_t Bs[2 * 128 * 32];   // 16 KB
  const int tid = threadIdx.x;
  const int w = tid >> 6, l = tid & 63;
  const int id = blockIdx.x;
  const int xcd = id & 7;
  const int t2 = id >> 3;
  const int nmq = (int)(gridDim.x >> 3) / GN;
  const int nt = t2 / nmq;
  const int mq = t2 - nt * nmq;
  const int mt = (mq << 3) + xcd;
  const int m0 = mt << 6, n0 = nt << 7;
  const int wm = (w >> 1) << 5, wn = (w & 1) << 6;   // wave: 32x64 of the 64x128 tile
  const int rA = (w << 4) + (l >> 2);
  const int cA = (l & 3) << 3;
  const int fr = l & 15, fq = l >> 4;

  floatx4 acc[2][4];
#pragma unroll
  for (int i = 0; i < 2; i++)
#pragma unroll
    for (int j = 0; j < 4; j++) acc[i][j] = (floatx4)0.0f;

  const ushort_t* Ab = A + (size_t)(m0 + rA) * K + cA;
  const ushort_t* Bb = B + (size_t)(n0 + rA) * K + cA;
  const size_t row64 = (size_t)64 * K;

  for (int k0 = 0; k0 < K; k0 += 64){
    __syncthreads();
    gload16(Ab + k0, As + (w << 9));
    gload16(Ab + k0 + 32, As + 2048 + (w << 9));
    gload16(Bb + k0, Bs + (w << 9));
    gload16(Bb + row64 + k0, Bs + 2048 + (w << 9));
    gload16(Bb + k0 + 32, Bs + 4096 + (w << 9));
    gload16(Bb + row64 + k0 + 32, Bs + 6144 + (w << 9));
    __syncthreads();
#pragma unroll
    for (int h = 0; h < 2; h++){
      const ushort_t* Ah = As + (h << 11);
      const ushort_t* Bh = Bs + (h << 12);
      short8 af[2], bg[4];
#pragma unroll
      for (int i = 0; i < 2; i++)
        af[i] = *(const short8*)(Ah + ((wm + (i << 4) + fr) << 5) + (fq << 3));
#pragma unroll
      for (int j = 0; j < 4; j++)
        bg[j] = *(const short8*)(Bh + ((wn + (j << 4) + fr) << 5) + (fq << 3));
#pragma unroll
      for (int i = 0; i < 2; i++)
#pragma unroll
        for (int j = 0; j < 4; j++)
          acc[i][j] = __builtin_amdgcn_mfma_f32_16x16x32_bf16(af[i], bg[j], acc[i][j], 0, 0, 0);
    }
  }

#pragma unroll
  for (int i = 0; i < 2; i++){
    int row = m0 + wm + (i << 4) + (fq << 2);
#pragma unroll
    for (int j = 0; j < 4; j++){
      int col = n0 + wn + (j << 4) + fr;
      float b = (MODE >= 2) ? bias[col] : 0.0f;
#pragma unroll
      for (int r = 0; r < 4; r++){
        float v = acc[i][j][r] + b;
        size_t idx = (size_t)(row + r) * N + col;
        if (MODE == 2) v += Xadd[idx];
        if (MODE == 4) ((float*)C)[idx] = v;
        else           ((ushort_t*)C)[idx] = f2bf(v);
      }
    }
  }
}

// ---------------- fused attention: logits+NPRE (MFMA) -> softmax/top-4 -> gsn -
__global__ __launch_bounds__(256) void k_attn(const ushort_t* __restrict__ T,
                                              const ushort_t* __restrict__ SNB,
                                              const ushort_t* __restrict__ PVB,
                                              const float* __restrict__ PBv,
                                              const float* __restrict__ CB,
                                              const float* __restrict__ TW,
                                              ushort_t* __restrict__ GSN){
  __shared__ float logit_s[4 * 256];
  __shared__ float attn_s[8 * 64];
  __shared__ float npr_s[8 * 256];
  __shared__ float nps_s[8 * 256];
  __shared__ float sc_s[8 * 32];
  __shared__ float tw_s[8 * 8];
  __shared__ float pb_s[32];
  __shared__ int   sel_s[8 * 4];
  __shared__ float tkw_s[8 * 4], rmax_s[8 * 4], rsum_s[8 * 4], fa_s[8 * 8], g_s[8 * 8];

  const int t = threadIdx.x;
  const int w = t >> 6, l = t & 63;
  const int tok0 = blockIdx.x << 3;
  const int pair = (blockIdx.x << 2) + w;

  { // MFMA: logits + NPRE for this wave's pair, fragments straight from global
    const size_t rbase = (size_t)pair * 16 + (l & 15);
    const int ko = (l >> 4) << 3;
    const ushort_t* Ap = T   + rbase * 1024 + ko;
    const ushort_t* Bp = SNB + rbase * 1024 + ko;
    const ushort_t* P0 = PVB + (size_t)(l & 15) * 1024 + ko;          // patterns 0-15
    const ushort_t* P1 = P0 + 16 * 1024;                              // patterns 16-31
    floatx4 aL = (floatx4)0.0f, aP0 = (floatx4)0.0f, aP1 = (floatx4)0.0f;
#pragma unroll 4
    for (int k0 = 0; k0 < 1024; k0 += 32){
      short8 b = *(const short8*)(Bp + k0);
      aL  = __builtin_amdgcn_mfma_f32_16x16x32_bf16(*(const short8*)(Ap + k0), b, aL, 0, 0, 0);
      aP0 = __builtin_amdgcn_mfma_f32_16x16x32_bf16(*(const short8*)(P0 + k0), b, aP0, 0, 0, 0);
      aP1 = __builtin_amdgcn_mfma_f32_16x16x32_bf16(*(const short8*)(P1 + k0), b, aP1, 0, 0, 0);
    }
    const int col = l & 15, r0 = (l >> 4) << 2;
#pragma unroll
    for (int r = 0; r < 4; r++)
      logit_s[(w << 8) + (r0 + r) * 16 + col] = aL[r] * 0.03125f;
    // NPRE: D[i][j] = PV_i . SN_j ; j -> (token j>>3, k=j&7), i -> pattern
    const int tokloc = (w << 1) + (col >> 3), kk = col & 7;
#pragma unroll
    for (int r = 0; r < 4; r++){
      npr_s[(tokloc << 8) + kk * 32 + (r0 + r)]      = aP0[r];
      npr_s[(tokloc << 8) + kk * 32 + (r0 + r) + 16] = aP1[r];
    }
  }
  if (t < 64) tw_s[t] = TW[(tok0 << 3) + t];
  if (t < 32) pb_s[t] = PBv[t];
  __syncthreads();

  const int loc = t >> 5, q = t & 31;    // token-in-block, lane-in-token-group
  if (q < 8){ // softmax of logit row q for token loc
    const float* lrow = logit_s + ((loc >> 1) << 8) + (loc & 1) * 136 + q * 16;
    float a[8]; float m = -1e30f;
#pragma unroll
    for (int j = 0; j < 8; j++){ a[j] = lrow[j]; m = fmaxf(m, a[j]); }
    float s = 0.f;
#pragma unroll
    for (int j = 0; j < 8; j++){ a[j] = expf(a[j] - m); s += a[j]; }
    float inv = 1.f / s;
#pragma unroll
    for (int j = 0; j < 8; j++) attn_s[(loc << 6) + q * 8 + j] = a[j] * inv;
  }
  __syncthreads();

  { // nps: column qq = q&7, patterns (q>>3)*8..+7 ; +pb (rows of attn sum to 1)
    const int qq = q & 7, p0 = (q >> 3) << 3;
    float a[8];
#pragma unroll
    for (int k = 0; k < 8; k++) a[k] = attn_s[(loc << 6) + qq * 8 + k];
    const float* np = npr_s + (loc << 8);
    float* npsr = nps_s + (loc << 8);
    for (int p = p0; p < p0 + 8; p++){
      float acc = pb_s[p];
#pragma unroll
      for (int k = 0; k < 8; k++) acc += a[k] * np[k * 32 + p];
      npsr[p * 8 + qq] = acc * 0.03125f;
    }
  }
  __syncthreads();

  { // scores, p = q
    const float* npsr = nps_s + (loc << 8);
    float nb = 0.f;
#pragma unroll
    for (int qq = 0; qq < 8; qq++) nb += npsr[q * 8 + qq] * tw_s[(loc << 3) + qq];
    sc_s[(loc << 5) + q] = 0.5f * nb + 0.5f * CB[((size_t)(tok0 + loc) << 5) + q];
  }
  __syncthreads();

  if (q == 0){ // top-4 (stable: first index wins ties, like lax.top_k)
    const float* sc = sc_s + (loc << 5);
    unsigned used = 0; float vals[4]; int idx[4];
    for (int kp = 0; kp < 4; kp++){
      float best = -1e30f; int bi = 0;
      for (int p = 0; p < 32; p++)
        if (!((used >> p) & 1u) && sc[p] > best){ best = sc[p]; bi = p; }
      used |= 1u << bi; vals[kp] = best; idx[kp] = bi;
    }
    float mm = vals[0], ss = 0.f, e[4];
    for (int kp = 0; kp < 4; kp++){ e[kp] = expf(vals[kp] - mm); ss += e[kp]; }
    for (int kp = 0; kp < 4; kp++){ tkw_s[(loc << 2) + kp] = e[kp] / ss; sel_s[(loc << 2) + kp] = idx[kp]; }
  }
  __syncthreads();

  if (q < 4){ // row softmax stats for selected patterns
    const float* npsr = nps_s + (loc << 8);
    int p = sel_s[(loc << 2) + q];
    float mm = -1e30f;
    for (int j = 0; j < 8; j++) mm = fmaxf(mm, npsr[p * 8 + j]);
    float ss = 0.f;
    for (int j = 0; j < 8; j++) ss += expf(npsr[p * 8 + j] - mm);
    rmax_s[(loc << 2) + q] = mm; rsum_s[(loc << 2) + q] = ss;
  }
  __syncthreads();

  if (q < 8){ // final_attn
    const float* npsr = nps_s + (loc << 8);
    float f = 0.f;
    for (int kp = 0; kp < 4; kp++){
      int p = sel_s[(loc << 2) + kp];
      f += tkw_s[(loc << 2) + kp] * expf(npsr[p * 8 + q] - rmax_s[(loc << 2) + kp]) / rsum_s[(loc << 2) + kp];
    }
    fa_s[(loc << 3) + q] = f;
  }
  __syncthreads();

  if (q < 8){ // g = fa @ attn
    float g = 0.f;
    for (int qq = 0; qq < 8; qq++) g += fa_s[(loc << 3) + qq] * attn_s[(loc << 6) + qq * 8 + q];
    g_s[(loc << 3) + q] = g;
  }
  __syncthreads();

  // gsn: each wave handles its pair's 2 tokens; SNB rows are L1/L2-hot
  for (int tl = 0; tl < 2; tl++){
    const int tkl = (w << 1) + tl;
    const size_t tok = (size_t)tok0 + tkl;
    float o[16];
#pragma unroll
    for (int i = 0; i < 16; i++) o[i] = 0.f;
#pragma unroll
    for (int k = 0; k < 8; k++){
      float gk = g_s[(tkl << 3) + k];
      const uint4* src = (const uint4*)(SNB + ((tok << 3) + k) * 1024 + (l << 4));
      float f0[8], f1[8];
      unpack8(src[0], f0);
      unpack8(src[1], f1);
#pragma unroll
      for (int i = 0; i < 8; i++){ o[i] += gk * f0[i]; o[8 + i] += gk * f1[i]; }
    }
    uint4* dst = (uint4*)(GSN + tok * 1024 + (l << 4));
    dst[0] = pack8(o);
    dst[1] = pack8(o + 8);
  }
}

extern "C" void kernel_launch(void* const* d_in, const int* in_sizes, int n_in,
                              void* d_out, int out_size, void* d_ws, size_t ws_size,
                              hipStream_t stream){
  (void)in_sizes; (void)n_in; (void)out_size; (void)ws_size;
  const float* x   = (const float*)d_in[0];
  const float* tw  = (const float*)d_in[3];
  const float* SN  = (const float*)d_in[4];
  const float* ctx = (const float*)d_in[5];
  const float* Wq  = (const float*)d_in[6];
  const float* bq  = (const float*)d_in[7];
  const float* Wk  = (const float*)d_in[8];
  const float* Wv  = (const float*)d_in[10];
  const float* bv  = (const float*)d_in[11];
  const float* pat = (const float*)d_in[12];
  const float* Wup = (const float*)d_in[13];
  const float* bup = (const float*)d_in[14];
  const float* Wdn = (const float*)d_in[15];
  const float* bdn = (const float*)d_in[16];
  float* out = (float*)d_out;

  char* ws = (char*)d_ws;
  size_t off = 0;
  auto alloc = [&](size_t bytes) -> char* {
    char* p = ws + off;
    off = (off + bytes + 255) & ~(size_t)255;
    return p;
  };
  ushort_t* SNB  = (ushort_t*)alloc(67108864);  // SN bf16 [32768][1024]; later aliased by H
  ushort_t* TB   = (ushort_t*)alloc(67108864);  // T bf16; later aliased by COMBINED
  float*    CBb  = (float*)alloc(524288);       // [4096][32]
  ushort_t* GSN  = (ushort_t*)alloc(8388608);   // [4096][1024] bf16
  ushort_t* CTXB = (ushort_t*)alloc(8388608);
  ushort_t* PATB = (ushort_t*)alloc(65536);
  ushort_t* WVB  = (ushort_t*)alloc(2097152);
  ushort_t* WUPB = (ushort_t*)alloc(8388608);
  ushort_t* WDNB = (ushort_t*)alloc(8388608);
  ushort_t* ATB  = (ushort_t*)alloc(2097152);
  ushort_t* WKTB = (ushort_t*)alloc(2097152);
  ushort_t* WQTB = (ushort_t*)alloc(2097152);
  ushort_t* WVTB = (ushort_t*)alloc(2097152);
  ushort_t* PVB  = (ushort_t*)alloc(65536);
  float*    WVEC = (float*)alloc(4096);
  float*    PBv  = (float*)alloc(128);
  ushort_t* H    = SNB;   // 32MB alias (SNB dead by FFN time)
  ushort_t* CMB  = TB;    // 8MB alias (T dead after k_attn)

  // converts (one launch) + transposes (one) + prep incl. CB (one)
  const int e0 = 8388608, e1 = e0 + 1048576, e2 = e1 + 8192,
            e3 = e2 + 262144, e4 = e3 + 1048576, e5 = e4 + 1048576;
  k_cvt_multi<<<(e5 + 255) / 256, 256, 0, stream>>>(
      SN, SNB, e0, ctx, CTXB, e1, pat, PATB, e2,
      Wv, WVB, e3, Wup, WUPB, e4, Wdn, WDNB, e5);
  k_transpose3<<<dim3(32, 32, 3), 256, 0, stream>>>(Wq, WQTB, Wk, WKTB, Wv, WVTB);
  k_prep<<<552, 256, 0, stream>>>(bq, WKTB, WVEC, pat, bv, PBv, WVTB, PATB, PVB, CTXB, CBb);

  // At[d'][d] = sum_e Wk[e][d']*Wq[e][d]   (64x128 tiles, 128 blocks)
  k_gemm_bt64<0, 8><<<128, 256, 0, stream>>>(WKTB, WQTB, ATB, nullptr, nullptr, 1024, 1024);
  // T = SN @ At^T + wvec   (256x256; 128 m-tiles x 4 n-tiles = 512 blocks)
  k_gemm8<1><<<512, 512, 0, stream>>>(SNB, ATB, TB, WVEC, 1024, 1024, 4);
  // fused: logits+NPRE (MFMA) -> softmax/top-4/final_attn -> gsn
  k_attn<<<512, 256, 0, stream>>>(TB, SNB, PVB, PBv, CBb, tw, GSN);
  // combined = gsn @ Wv^T + bv + x   (bf16, 64x128 tiles, 512 blocks)
  k_gemm_bt64<2, 8><<<512, 256, 0, stream>>>(GSN, WVB, CMB, bv, x, 1024, 1024);
  // H = gelu(combined @ Wup^T + bup)  (256x256; 16 m x 16 n = 256 blocks)
  k_gemm8<3><<<256, 512, 0, stream>>>(CMB, WUPB, H, bup, 4096, 1024, 16);
  // out = H @ Wdown^T + bdn  (fp32, 64x128 tiles, 512 blocks)
  k_gemm_bt64<4, 8><<<512, 256, 0, stream>>>(H, WDNB, out, bdn, nullptr, 1024, 4096);
}

// Round 9
// 541.453 us; speedup vs baseline: 1.0456x; 1.0456x over previous
//
#include <hip/hip_runtime.h>
#include <math.h>

// B=2,S=2048 -> NT=4096 tokens; K=8, D=1024, P=32, KP=4, DFF=4096
typedef unsigned short ushort_t;
typedef __attribute__((ext_vector_type(8))) short short8;
typedef __attribute__((ext_vector_type(4))) float floatx4;

static __device__ __forceinline__ ushort_t f2bf(float f){
  unsigned int u = __float_as_uint(f);
  unsigned int r = u + 0x7FFFu + ((u >> 16) & 1u);   // round-to-nearest-even
  return (ushort_t)(r >> 16);
}
static __device__ __forceinline__ void unpack8(uint4 u, float* f){
  f[0] = __uint_as_float(u.x << 16); f[1] = __uint_as_float(u.x & 0xffff0000u);
  f[2] = __uint_as_float(u.y << 16); f[3] = __uint_as_float(u.y & 0xffff0000u);
  f[4] = __uint_as_float(u.z << 16); f[5] = __uint_as_float(u.z & 0xffff0000u);
  f[6] = __uint_as_float(u.w << 16); f[7] = __uint_as_float(u.w & 0xffff0000u);
}
static __device__ __forceinline__ uint4 pack8(const float* f){
  uint4 u;
  u.x = (unsigned)f2bf(f[0]) | ((unsigned)f2bf(f[1]) << 16);
  u.y = (unsigned)f2bf(f[2]) | ((unsigned)f2bf(f[3]) << 16);
  u.z = (unsigned)f2bf(f[4]) | ((unsigned)f2bf(f[5]) << 16);
  u.w = (unsigned)f2bf(f[6]) | ((unsigned)f2bf(f[7]) << 16);
  return u;
}

static __device__ __forceinline__ void gload16(const void* g, void* l){
  __builtin_amdgcn_global_load_lds((const __attribute__((address_space(1))) void*)g,
                                   (__attribute__((address_space(3))) void*)l, 16, 0, 0);
}

// gelu(x) ~= x * sigmoid(1.5957691216 x + 0.0713548162 x^3)  (tanh form, hw exp)
static __device__ __forceinline__ float gelu_f(float v){
  float w = v * (-1.5957691216f - 0.0713548162f * v * v);
  return v / (1.0f + __expf(w));
}

// ------- merged fp32 -> bf16 converts (6 tensors) + 3x1024x1024 transpose ----
__global__ __launch_bounds__(256) void k_cvt_tr(
    const float* __restrict__ s0, ushort_t* __restrict__ d0, int e0,
    const float* __restrict__ s1, ushort_t* __restrict__ d1, int e1,
    const float* __restrict__ s2, ushort_t* __restrict__ d2, int e2,
    const float* __restrict__ s3, ushort_t* __restrict__ d3, int e3,
    const float* __restrict__ s4, ushort_t* __restrict__ d4, int e4,
    const float* __restrict__ s5, ushort_t* __restrict__ d5, int e5,
    const float* __restrict__ t0, ushort_t* __restrict__ u0,
    const float* __restrict__ t1, ushort_t* __restrict__ u1,
    const float* __restrict__ t2, ushort_t* __restrict__ u2,
    int cvt_blocks){
  __shared__ float tile[32][33];
  const int bid = blockIdx.x;
  if (bid < cvt_blocks){
    int i = bid * 256 + threadIdx.x;
    const float* s; ushort_t* d; int b;
    if      (i < e0){ s = s0; d = d0; b = 0;  }
    else if (i < e1){ s = s1; d = d1; b = e0; }
    else if (i < e2){ s = s2; d = d2; b = e1; }
    else if (i < e3){ s = s3; d = d3; b = e2; }
    else if (i < e4){ s = s4; d = d4; b = e3; }
    else if (i < e5){ s = s5; d = d5; b = e4; }
    else return;
    int j = i - b;
    float4 v = ((const float4*)s)[j];
    unsigned long long p = (unsigned long long)f2bf(v.x)
                         | ((unsigned long long)f2bf(v.y) << 16)
                         | ((unsigned long long)f2bf(v.z) << 32)
                         | ((unsigned long long)f2bf(v.w) << 48);
    ((unsigned long long*)d)[j] = p;
    return;
  }
  // transpose part: 3072 blocks, z = tb>>10, 32x32 tiles
  const int tb = bid - cvt_blocks;
  const int z = tb >> 10, rem = tb & 1023;
  const int by = (rem >> 5) << 5, bx = (rem & 31) << 5;
  const float* in; ushort_t* out;
  if      (z == 0){ in = t0; out = u0; }
  else if (z == 1){ in = t1; out = u1; }
  else            { in = t2; out = u2; }
  int tx = threadIdx.x & 31, ty = threadIdx.x >> 5;   // ty 0..7
  for (int i = 0; i < 32; i += 8)
    tile[ty + i][tx] = in[(size_t)(by + ty + i) * 1024 + bx + tx];
  __syncthreads();
  for (int i = 0; i < 32; i += 8)
    out[(size_t)(bx + ty + i) * 1024 + by + tx] = f2bf(tile[tx][ty + i]);
}

// -- merged prep: wvec(256) | pb(8) | PV(256) | CB n32-GEMM(32) | ATB GEMM(128)
__global__ __launch_bounds__(256) void k_prep(const float* __restrict__ bq,
                                              const ushort_t* __restrict__ WKT,
                                              float* __restrict__ wv,
                                              const float* __restrict__ pat,
                                              const float* __restrict__ bv,
                                              float* __restrict__ pb,
                                              const ushort_t* __restrict__ WVT,
                                              const ushort_t* __restrict__ PATB,
                                              ushort_t* __restrict__ PVB,
                                              const ushort_t* __restrict__ CTXB,
                                              float* __restrict__ CBb,
                                              const ushort_t* __restrict__ WQT,
                                              ushort_t* __restrict__ ATBo){
  __shared__ ushort_t As[128 * 32];    // 8 KB
  __shared__ ushort_t Bs[2 * 128 * 32];// 16 KB (CB uses first 2KB; ATB uses all)
  const int bid = blockIdx.x;
  const int l = threadIdx.x & 63;
  if (bid < 256){            // wvec
    int d = (bid << 2) + (threadIdx.x >> 6);
    const uint4* row = (const uint4*)(WKT + (size_t)d * 1024 + (l << 4));
    const float4* b4 = (const float4*)(bq + (l << 4));
    float w[16], bb[16];
    unpack8(row[0], w); unpack8(row[1], w + 8);
#pragma unroll
    for (int i = 0; i < 4; i++){
      float4 v = b4[i];
      bb[i*4] = v.x; bb[i*4+1] = v.y; bb[i*4+2] = v.z; bb[i*4+3] = v.w;
    }
    float a = 0.f;
#pragma unroll
    for (int i = 0; i < 16; i++) a += w[i] * bb[i];
#pragma unroll
    for (int s = 1; s < 64; s <<= 1) a += __shfl_xor(a, s);
    if (l == 0) wv[d] = a;
  } else if (bid < 264){     // pb
    int p = ((bid - 256) << 2) + (threadIdx.x >> 6);
    const float4* pr = (const float4*)(pat + p * 1024) + l;
    const float4* b4 = (const float4*)bv + l;
    float a = 0.f;
#pragma unroll
    for (int i = 0; i < 4; i++){
      float4 x = pr[i * 64], y = b4[i * 64];
      a += x.x * y.x + x.y * y.y + x.z * y.z + x.w * y.w;
    }
#pragma unroll
    for (int s = 1; s < 64; s <<= 1) a += __shfl_xor(a, s);
    if (l == 0) pb[p] = a;
  } else if (bid < 520){     // PV
    int d = ((bid - 264) << 2) + (threadIdx.x >> 6);
    const uint4* wr = (const uint4*)(WVT + (size_t)d * 1024 + (l << 4));
    float w[16];
    unpack8(wr[0], w); unpack8(wr[1], w + 8);
    for (int p = 0; p < 32; p++){
      const uint4* pr = (const uint4*)(PATB + p * 1024 + (l << 4));
      float pw[16];
      unpack8(pr[0], pw); unpack8(pr[1], pw + 8);
      float a = 0.f;
#pragma unroll
      for (int i = 0; i < 16; i++) a += w[i] * pw[i];
#pragma unroll
      for (int s = 1; s < 64; s <<= 1) a += __shfl_xor(a, s);
      if (l == 0) PVB[p * 1024 + d] = f2bf(a);
    }
  } else if (bid < 552){     // CB[tok][p] = ctx_tok . pat_p  (n32 MFMA GEMM)
    const int tid = threadIdx.x;
    const int w = tid >> 6;
    const int m0 = (bid - 520) << 7;
    const int rA = (w << 4) + (l >> 2);
    const int cA = (l & 3) << 3;
    const int fr = l & 15, fq = l >> 4;
    const int K = 1024;
    floatx4 acc[2][2];
#pragma unroll
    for (int i = 0; i < 2; i++)
#pragma unroll
      for (int j = 0; j < 2; j++) acc[i][j] = (floatx4)0.0f;
    const ushort_t* Ab = CTXB + (size_t)(m0 + rA) * K + cA;
    const ushort_t* Bb = PATB + (size_t)rA * K + cA;
    const size_t row64 = (size_t)64 * K;
    for (int k0 = 0; k0 < K; k0 += 32){
      __syncthreads();
      gload16(Ab + k0, As + (w << 9));
      gload16(Ab + row64 + k0, As + 2048 + (w << 9));
      if (w < 2) gload16(Bb + k0, Bs + (w << 9));
      __syncthreads();
      short8 af[2], bg[2];
#pragma unroll
      for (int i = 0; i < 2; i++)
        af[i] = *(const short8*)(As + (((w << 5) + (i << 4) + fr) << 5) + (fq << 3));
#pragma unroll
      for (int j = 0; j < 2; j++)
        bg[j] = *(const short8*)(Bs + (((j << 4) + fr) << 5) + (fq << 3));
#pragma unroll
      for (int i = 0; i < 2; i++)
#pragma unroll
        for (int j = 0; j < 2; j++)
          acc[i][j] = __builtin_amdgcn_mfma_f32_16x16x32_bf16(af[i], bg[j], acc[i][j], 0, 0, 0);
    }
#pragma unroll
    for (int i = 0; i < 2; i++){
      int row = m0 + (w << 5) + (i << 4) + (fq << 2);
#pragma unroll
      for (int j = 0; j < 2; j++){
        int col = (j << 4) + fr;
#pragma unroll
        for (int r = 0; r < 4; r++)
          CBb[(size_t)(row + r) * 32 + col] = acc[i][j][r];
      }
    }
  } else {                   // ATB[d'][d] = sum_e Wk[e][d']*Wq[e][d] (64x128 tiles)
    const int tid = threadIdx.x;
    const int w = tid >> 6;
    const int id = bid - 552;            // 0..127
    const int xcd = id & 7, t2 = id >> 3;
    const int nt = t2 >> 1, mq = t2 & 1;
    const int mt = (mq << 3) + xcd;
    const int m0 = mt << 6, n0 = nt << 7;
    const int wm = (w >> 1) << 5, wn = (w & 1) << 6;
    const int rA = (w << 4) + (l >> 2);
    const int cA = (l & 3) << 3;
    const int fr = l & 15, fq = l >> 4;
    const int K = 1024, N = 1024;
    floatx4 acc[2][4];
#pragma unroll
    for (int i = 0; i < 2; i++)
#pragma unroll
      for (int j = 0; j < 4; j++) acc[i][j] = (floatx4)0.0f;
    const ushort_t* Ab = WKT + (size_t)(m0 + rA) * K + cA;
    const ushort_t* Bb = WQT + (size_t)(n0 + rA) * K + cA;
    const size_t row64 = (size_t)64 * K;
    for (int k0 = 0; k0 < K; k0 += 64){
      __syncthreads();
      gload16(Ab + k0, As + (w << 9));
      gload16(Ab + k0 + 32, As + 2048 + (w << 9));
      gload16(Bb + k0, Bs + (w << 9));
      gload16(Bb + row64 + k0, Bs + 2048 + (w << 9));
      gload16(Bb + k0 + 32, Bs + 4096 + (w << 9));
      gload16(Bb + row64 + k0 + 32, Bs + 6144 + (w << 9));
      __syncthreads();
#pragma unroll
      for (int h = 0; h < 2; h++){
        const ushort_t* Ah = As + (h << 11);
        const ushort_t* Bh = Bs + (h << 12);
        short8 af[2], bg[4];
#pragma unroll
        for (int i = 0; i < 2; i++)
          af[i] = *(const short8*)(Ah + ((wm + (i << 4) + fr) << 5) + (fq << 3));
#pragma unroll
        for (int j = 0; j < 4; j++)
          bg[j] = *(const short8*)(Bh + ((wn + (j << 4) + fr) << 5) + (fq << 3));
#pragma unroll
        for (int i = 0; i < 2; i++)
#pragma unroll
          for (int j = 0; j < 4; j++)
            acc[i][j] = __builtin_amdgcn_mfma_f32_16x16x32_bf16(af[i], bg[j], acc[i][j], 0, 0, 0);
      }
    }
#pragma unroll
    for (int i = 0; i < 2; i++){
      int row = m0 + wm + (i << 4) + (fq << 2);
#pragma unroll
      for (int j = 0; j < 4; j++){
        int col = n0 + wn + (j << 4) + fr;
#pragma unroll
        for (int r = 0; r < 4; r++)
          ATBo[(size_t)(row + r) * N + col] = f2bf(acc[i][j][r]);
      }
    }
  }
}

// =============== 256x256-tile 4-phase GEMM (R4-best schedule) ================
// 512 threads = 8 waves (2M x 4N). BK=64. LDS 128 KiB dbuf.
// Phase p of tile t: ds_read subtile | stage 1 half-tile of t+1 | barrier |
// lgkmcnt(0)+sched_fence | setprio(1) 16xMFMA setprio(0) | [vmcnt(4)] barrier.
// Stagger A0,B0,B1,A1; every wait targets loads issued >=2 phases earlier.
// Only the rule-#18 sched_barrier (after lgkmcnt(0)) is kept — asm memory
// clobbers already order all memory ops; extra pins regress (m141).
// LDS swizzle: byte ^= (row&7)<<4 involution on stage-src AND read (rule #21).
// MODE 1: bf16(acc+bias)  MODE 3: bf16(gelu(acc+bias))
#define SBAR_  __builtin_amdgcn_s_barrier()
#define SCHED_ __builtin_amdgcn_sched_barrier(0)
#define LGKM0_ asm volatile("s_waitcnt lgkmcnt(0)" ::: "memory")
#define VM4_   asm volatile("s_waitcnt vmcnt(4)" ::: "memory")
#define VM2_   asm volatile("s_waitcnt vmcnt(2)" ::: "memory")
#define VM0_   asm volatile("s_waitcnt vmcnt(0)" ::: "memory")

#define STG_(Gp, Lp, qh, tt) do{ \
    const ushort_t* _g = (Gp) + (size_t)(((qh) << 7) + (wid << 3)) * K + ((tt) << 6); \
    char* _l = (Lp) + ((((tt) & 1) << 15) | ((qh) << 14) | (wid << 10)); \
    gload16(_g, _l); \
    gload16(_g + ((size_t)K << 6), _l + 8192); \
  }while(0)

#define RDA_(qm, cb) do{ \
    _Pragma("unroll") \
    for (int _i = 0; _i < 4; _i++){ \
      af[_i][0] = *(const short8*)(AsB + (cb) + ((qm) << 14) + arow + (_i << 11) + c0); \
      af[_i][1] = *(const short8*)(AsB + (cb) + ((qm) << 14) + arow + (_i << 11) + c1); \
    } }while(0)

#define RDB_(qn, cb) do{ \
    _Pragma("unroll") \
    for (int _j = 0; _j < 2; _j++){ \
      bg[qn][_j][0] = *(const short8*)(BsB + (cb) + ((qn) << 14) + brow + (_j << 11) + c0); \
      bg[qn][_j][1] = *(const short8*)(BsB + (cb) + ((qn) << 14) + brow + (_j << 11) + c1); \
    } }while(0)

#define MFMA_(qm, qn) do{ \
    _Pragma("unroll") \
    for (int _i = 0; _i < 4; _i++) \
    _Pragma("unroll") \
      for (int _j = 0; _j < 2; _j++){ \
        acc[qm][_i][qn][_j] = __builtin_amdgcn_mfma_f32_16x16x32_bf16(af[_i][0], bg[qn][_j][0], acc[qm][_i][qn][_j], 0, 0, 0); \
        acc[qm][_i][qn][_j] = __builtin_amdgcn_mfma_f32_16x16x32_bf16(af[_i][1], bg[qn][_j][1], acc[qm][_i][qn][_j], 0, 0, 0); \
      } }while(0)

template<int MODE>
__global__ __launch_bounds__(512, 2) void k_gemm8(const ushort_t* __restrict__ A,
                                                  const ushort_t* __restrict__ B,
                                                  void* __restrict__ C,
                                                  const float* __restrict__ bias,
                                                  int N, int K, int ntn){
  __shared__ __align__(16) ushort_t As[2 * 256 * 64];   // 64 KB
  __shared__ __align__(16) ushort_t Bs[2 * 256 * 64];   // 64 KB
  const int tid = threadIdx.x;
  const int wid = tid >> 6, l = tid & 63;
  const int wr = wid >> 2, wc = wid & 3;
  const int fr = l & 15, fq = l >> 4;
  const int id = blockIdx.x;
  const int xcd = id & 7, t2 = id >> 3;
  const int nt = t2 % ntn, mq = t2 / ntn;
  const int mt = (mq << 3) + xcd;
  const int m0 = mt << 8, n0 = nt << 8;
  const int NT = K >> 6;

  // staging: lane l of chunk c loads global row c*8+(l>>3), 16B-block (l&7)^(l>>3)
  const int sgr = l >> 3;
  const int sgc = ((l & 7) ^ (l >> 3)) << 3;
  const ushort_t* Ag = A + (size_t)(m0 + sgr) * K + sgc;
  const ushort_t* Bg = B + (size_t)(n0 + sgr) * K + sgc;
  char* AsB = (char*)As;
  char* BsB = (char*)Bs;
  // ds_read: swizzled col16 = col16lin ^ (row&7); row&7 == fr&7 here
  const int c0 = ((fq ^ (fr & 7)) << 4);
  const int c1 = (((4 | fq) ^ (fr & 7)) << 4);
  const int arow = (wr << 13) + fr * 128;     // + qm*16384 + i*2048
  const int brow = (wc << 12) + fr * 128;     // + qn*16384 + j*2048

  floatx4 acc[2][4][2][2];
#pragma unroll
  for (int a = 0; a < 2; a++)
#pragma unroll
    for (int b = 0; b < 4; b++)
#pragma unroll
      for (int c = 0; c < 2; c++)
#pragma unroll
        for (int d = 0; d < 2; d++) acc[a][b][c][d] = (floatx4)0.0f;
  short8 af[4][2], bg[2][2][2];

  // prologue: stage tile 0 (order = first-use order), guarantee A0,B0
  STG_(Ag, AsB, 0, 0);
  STG_(Bg, BsB, 0, 0);
  STG_(Bg, BsB, 1, 0);
  STG_(Ag, AsB, 1, 0);
  VM4_; SBAR_;

#pragma unroll 2
  for (int t = 0; t < NT - 1; t++){
    const int cur = (t & 1) << 15;
    const int tn = t + 1;
    // ph1: quad(0,0); stage A0(t+1); trailing vm drains B1(t)
    RDA_(0, cur); RDB_(0, cur);
    STG_(Ag, AsB, 0, tn);
    SBAR_; LGKM0_; SCHED_;
    __builtin_amdgcn_s_setprio(1); MFMA_(0, 0); __builtin_amdgcn_s_setprio(0);
    VM4_; SBAR_;
    // ph2: quad(0,1); stage B0(t+1); trailing vm drains A1(t)
    RDB_(1, cur);
    STG_(Bg, BsB, 0, tn);
    SBAR_; LGKM0_; SCHED_;
    __builtin_amdgcn_s_setprio(1); MFMA_(0, 1); __builtin_amdgcn_s_setprio(0);
    VM4_; SBAR_;
    // ph3: quad(1,1); stage B1(t+1); no trailing vm (ph4 reads nothing)
    RDA_(1, cur);
    STG_(Bg, BsB, 1, tn);
    SBAR_; LGKM0_; SCHED_;
    __builtin_amdgcn_s_setprio(1); MFMA_(1, 1); __builtin_amdgcn_s_setprio(0);
    SBAR_;
    // ph4: quad(1,0) (reuses af(qm1), bg[0]); stage A1(t+1); vm drains A0,B0(t+1)
    STG_(Ag, AsB, 1, tn);
    SBAR_;
    __builtin_amdgcn_s_setprio(1); MFMA_(1, 0); __builtin_amdgcn_s_setprio(0);
    VM4_; SBAR_;
  }
  { // peeled last tile: no staging; drain 2 -> 0
    const int cur = ((NT - 1) & 1) << 15;
    RDA_(0, cur); RDB_(0, cur);
    SBAR_; LGKM0_; SCHED_;
    __builtin_amdgcn_s_setprio(1); MFMA_(0, 0); __builtin_amdgcn_s_setprio(0);
    VM2_; SBAR_;
    RDB_(1, cur);
    SBAR_; LGKM0_; SCHED_;
    __builtin_amdgcn_s_setprio(1); MFMA_(0, 1); __builtin_amdgcn_s_setprio(0);
    VM0_; SBAR_;
    RDA_(1, cur);
    SBAR_; LGKM0_; SCHED_;
    __builtin_amdgcn_s_setprio(1); MFMA_(1, 1); MFMA_(1, 0); __builtin_amdgcn_s_setprio(0);
  }

  // epilogue
#pragma unroll
  for (int qm = 0; qm < 2; qm++)
#pragma unroll
    for (int i = 0; i < 4; i++){
      const int row = m0 + (qm << 7) + (wr << 6) + (i << 4) + (fq << 2);
#pragma unroll
      for (int qn = 0; qn < 2; qn++)
#pragma unroll
        for (int j = 0; j < 2; j++){
          const int col = n0 + (qn << 7) + (wc << 5) + (j << 4) + fr;
          const float bsv = bias[col];
#pragma unroll
          for (int r = 0; r < 4; r++){
            float v = acc[qm][i][qn][j][r] + bsv;
            if (MODE == 3) v = gelu_f(v);
            ((ushort_t*)C)[(size_t)(row + r) * N + col] = f2bf(v);
          }
        }
    }
}

// ---------- 64x128-tile GEMM, BK=64 double-stage (small-M shapes) ------------
// Per-XCD enumeration nt-outer -> B-tile L2-resident across the mq sweep.
// MODE 0: bf16(acc) 2: bf16(acc+bias+Xadd) 4: fp32(acc+bias)
template<int MODE, int GN>
__global__ __launch_bounds__(256) void k_gemm_bt64(const ushort_t* __restrict__ A,
                                                   const ushort_t* __restrict__ B,
                                                   void* __restrict__ C,
                                                   const float* __restrict__ bias,
                                                   const float* __restrict__ Xadd,
                                                   int N, int K){
  __shared__ ushort_t As[2 * 64 * 32];    // 8 KB
  __shared__ ushort_t Bs[2 * 128 * 32];   // 16 KB
  const int tid = threadIdx.x;
  const int w = tid >> 6, l = tid & 63;
  const int id = blockIdx.x;
  const int xcd = id & 7;
  const int t2 = id >> 3;
  const int nmq = (int)(gridDim.x >> 3) / GN;
  const int nt = t2 / nmq;
  const int mq = t2 - nt * nmq;
  const int mt = (mq << 3) + xcd;
  const int m0 = mt << 6, n0 = nt << 7;
  const int wm = (w >> 1) << 5, wn = (w & 1) << 6;   // wave: 32x64 of the 64x128 tile
  const int rA = (w << 4) + (l >> 2);
  const int cA = (l & 3) << 3;
  const int fr = l & 15, fq = l >> 4;

  floatx4 acc[2][4];
#pragma unroll
  for (int i = 0; i < 2; i++)
#pragma unroll
    for (int j = 0; j < 4; j++) acc[i][j] = (floatx4)0.0f;

  const ushort_t* Ab = A + (size_t)(m0 + rA) * K + cA;
  const ushort_t* Bb = B + (size_t)(n0 + rA) * K + cA;
  const size_t row64 = (size_t)64 * K;

  for (int k0 = 0; k0 < K; k0 += 64){
    __syncthreads();
    gload16(Ab + k0, As + (w << 9));
    gload16(Ab + k0 + 32, As + 2048 + (w << 9));
    gload16(Bb + k0, Bs + (w << 9));
    gload16(Bb + row64 + k0, Bs + 2048 + (w << 9));
    gload16(Bb + k0 + 32, Bs + 4096 + (w << 9));
    gload16(Bb + row64 + k0 + 32, Bs + 6144 + (w << 9));
    __syncthreads();
#pragma unroll
    for (int h = 0; h < 2; h++){
      const ushort_t* Ah = As + (h << 11);
      const ushort_t* Bh = Bs + (h << 12);
      short8 af[2], bg[4];
#pragma unroll
      for (int i = 0; i < 2; i++)
        af[i] = *(const short8*)(Ah + ((wm + (i << 4) + fr) << 5) + (fq << 3));
#pragma unroll
      for (int j = 0; j < 4; j++)
        bg[j] = *(const short8*)(Bh + ((wn + (j << 4) + fr) << 5) + (fq << 3));
#pragma unroll
      for (int i = 0; i < 2; i++)
#pragma unroll
        for (int j = 0; j < 4; j++)
          acc[i][j] = __builtin_amdgcn_mfma_f32_16x16x32_bf16(af[i], bg[j], acc[i][j], 0, 0, 0);
    }
  }

#pragma unroll
  for (int i = 0; i < 2; i++){
    int row = m0 + wm + (i << 4) + (fq << 2);
#pragma unroll
    for (int j = 0; j < 4; j++){
      int col = n0 + wn + (j << 4) + fr;
      float b = (MODE >= 2) ? bias[col] : 0.0f;
#pragma unroll
      for (int r = 0; r < 4; r++){
        float v = acc[i][j][r] + b;
        size_t idx = (size_t)(row + r) * N + col;
        if (MODE == 2) v += Xadd[idx];
        if (MODE == 4) ((float*)C)[idx] = v;
        else           ((ushort_t*)C)[idx] = f2bf(v);
      }
    }
  }
}

// ---------------- fused attention: logits+NPRE (MFMA) -> softmax/top-4 -> gsn -
__global__ __launch_bounds__(256) void k_attn(const ushort_t* __restrict__ T,
                                              const ushort_t* __restrict__ SNB,
                                              const ushort_t* __restrict__ PVB,
                                              const float* __restrict__ PBv,
                                              const float* __restrict__ CB,
                                              const float* __restrict__ TW,
                                              ushort_t* __restrict__ GSN){
  __shared__ float logit_s[4 * 256];
  __shared__ float attn_s[8 * 64];
  __shared__ float npr_s[8 * 256];
  __shared__ float nps_s[8 * 256];
  __shared__ float sc_s[8 * 32];
  __shared__ float tw_s[8 * 8];
  __shared__ float pb_s[32];
  __shared__ int   sel_s[8 * 4];
  __shared__ float tkw_s[8 * 4], rmax_s[8 * 4], rsum_s[8 * 4], fa_s[8 * 8], g_s[8 * 8];

  const int t = threadIdx.x;
  const int w = t >> 6, l = t & 63;
  const int tok0 = blockIdx.x << 3;
  const int pair = (blockIdx.x << 2) + w;

  { // MFMA: logits + NPRE for this wave's pair, fragments straight from global
    const size_t rbase = (size_t)pair * 16 + (l & 15);
    const int ko = (l >> 4) << 3;
    const ushort_t* Ap = T   + rbase * 1024 + ko;
    const ushort_t* Bp = SNB + rbase * 1024 + ko;
    const ushort_t* P0 = PVB + (size_t)(l & 15) * 1024 + ko;          // patterns 0-15
    const ushort_t* P1 = P0 + 16 * 1024;                              // patterns 16-31
    floatx4 aL = (floatx4)0.0f, aP0 = (floatx4)0.0f, aP1 = (floatx4)0.0f;
#pragma unroll 4
    for (int k0 = 0; k0 < 1024; k0 += 32){
      short8 b = *(const short8*)(Bp + k0);
      aL  = __builtin_amdgcn_mfma_f32_16x16x32_bf16(*(const short8*)(Ap + k0), b, aL, 0, 0, 0);
      aP0 = __builtin_amdgcn_mfma_f32_16x16x32_bf16(*(const short8*)(P0 + k0), b, aP0, 0, 0, 0);
      aP1 = __builtin_amdgcn_mfma_f32_16x16x32_bf16(*(const short8*)(P1 + k0), b, aP1, 0, 0, 0);
    }
    const int col = l & 15, r0 = (l >> 4) << 2;
#pragma unroll
    for (int r = 0; r < 4; r++)
      logit_s[(w << 8) + (r0 + r) * 16 + col] = aL[r] * 0.03125f;
    // NPRE: D[i][j] = PV_i . SN_j ; j -> (token j>>3, k=j&7), i -> pattern
    const int tokloc = (w << 1) + (col >> 3), kk = col & 7;
#pragma unroll
    for (int r = 0; r < 4; r++){
      npr_s[(tokloc << 8) + kk * 32 + (r0 + r)]      = aP0[r];
      npr_s[(tokloc << 8) + kk * 32 + (r0 + r) + 16] = aP1[r];
    }
  }
  if (t < 64) tw_s[t] = TW[(tok0 << 3) + t];
  if (t < 32) pb_s[t] = PBv[t];
  __syncthreads();

  const int loc = t >> 5, q = t & 31;    // token-in-block, lane-in-token-group
  if (q < 8){ // softmax of logit row q for token loc
    const float* lrow = logit_s + ((loc >> 1) << 8) + (loc & 1) * 136 + q * 16;
    float a[8]; float m = -1e30f;
#pragma unroll
    for (int j = 0; j < 8; j++){ a[j] = lrow[j]; m = fmaxf(m, a[j]); }
    float s = 0.f;
#pragma unroll
    for (int j = 0; j < 8; j++){ a[j] = expf(a[j] - m); s += a[j]; }
    float inv = 1.f / s;
#pragma unroll
    for (int j = 0; j < 8; j++) attn_s[(loc << 6) + q * 8 + j] = a[j] * inv;
  }
  __syncthreads();

  { // nps: column qq = q&7, patterns (q>>3)*8..+7 ; +pb (rows of attn sum to 1)
    const int qq = q & 7, p0 = (q >> 3) << 3;
    float a[8];
#pragma unroll
    for (int k = 0; k < 8; k++) a[k] = attn_s[(loc << 6) + qq * 8 + k];
    const float* np = npr_s + (loc << 8);
    float* npsr = nps_s + (loc << 8);
    for (int p = p0; p < p0 + 8; p++){
      float acc = pb_s[p];
#pragma unroll
      for (int k = 0; k < 8; k++) acc += a[k] * np[k * 32 + p];
      npsr[p * 8 + qq] = acc * 0.03125f;
    }
  }
  __syncthreads();

  { // scores, p = q
    const float* npsr = nps_s + (loc << 8);
    float nb = 0.f;
#pragma unroll
    for (int qq = 0; qq < 8; qq++) nb += npsr[q * 8 + qq] * tw_s[(loc << 3) + qq];
    sc_s[(loc << 5) + q] = 0.5f * nb + 0.5f * CB[((size_t)(tok0 + loc) << 5) + q];
  }
  __syncthreads();

  if (q == 0){ // top-4 (stable: first index wins ties, like lax.top_k)
    const float* sc = sc_s + (loc << 5);
    unsigned used = 0; float vals[4]; int idx[4];
    for (int kp = 0; kp < 4; kp++){
      float best = -1e30f; int bi = 0;
      for (int p = 0; p < 32; p++)
        if (!((used >> p) & 1u) && sc[p] > best){ best = sc[p]; bi = p; }
      used |= 1u << bi; vals[kp] = best; idx[kp] = bi;
    }
    float mm = vals[0], ss = 0.f, e[4];
    for (int kp = 0; kp < 4; kp++){ e[kp] = expf(vals[kp] - mm); ss += e[kp]; }
    for (int kp = 0; kp < 4; kp++){ tkw_s[(loc << 2) + kp] = e[kp] / ss; sel_s[(loc << 2) + kp] = idx[kp]; }
  }
  __syncthreads();

  if (q < 4){ // row softmax stats for selected patterns
    const float* npsr = nps_s + (loc << 8);
    int p = sel_s[(loc << 2) + q];
    float mm = -1e30f;
    for (int j = 0; j < 8; j++) mm = fmaxf(mm, npsr[p * 8 + j]);
    float ss = 0.f;
    for (int j = 0; j < 8; j++) ss += expf(npsr[p * 8 + j] - mm);
    rmax_s[(loc << 2) + q] = mm; rsum_s[(loc << 2) + q] = ss;
  }
  __syncthreads();

  if (q < 8){ // final_attn
    const float* npsr = nps_s + (loc << 8);
    float f = 0.f;
    for (int kp = 0; kp < 4; kp++){
      int p = sel_s[(loc << 2) + kp];
      f += tkw_s[(loc << 2) + kp] * expf(npsr[p * 8 + q] - rmax_s[(loc << 2) + kp]) / rsum_s[(loc << 2) + kp];
    }
    fa_s[(loc << 3) + q] = f;
  }
  __syncthreads();

  if (q < 8){ // g = fa @ attn
    float g = 0.f;
    for (int qq = 0; qq < 8; qq++) g += fa_s[(loc << 3) + qq] * attn_s[(loc << 6) + qq * 8 + q];
    g_s[(loc << 3) + q] = g;
  }
  __syncthreads();

  // gsn: each wave handles its pair's 2 tokens; SNB rows are L1/L2-hot
  for (int tl = 0; tl < 2; tl++){
    const int tkl = (w << 1) + tl;
    const size_t tok = (size_t)tok0 + tkl;
    float o[16];
#pragma unroll
    for (int i = 0; i < 16; i++) o[i] = 0.f;
#pragma unroll
    for (int k = 0; k < 8; k++){
      float gk = g_s[(tkl << 3) + k];
      const uint4* src = (const uint4*)(SNB + ((tok << 3) + k) * 1024 + (l << 4));
      float f0[8], f1[8];
      unpack8(src[0], f0);
      unpack8(src[1], f1);
#pragma unroll
      for (int i = 0; i < 8; i++){ o[i] += gk * f0[i]; o[8 + i] += gk * f1[i]; }
    }
    uint4* dst = (uint4*)(GSN + tok * 1024 + (l << 4));
    dst[0] = pack8(o);
    dst[1] = pack8(o + 8);
  }
}

extern "C" void kernel_launch(void* const* d_in, const int* in_sizes, int n_in,
                              void* d_out, int out_size, void* d_ws, size_t ws_size,
                              hipStream_t stream){
  (void)in_sizes; (void)n_in; (void)out_size; (void)ws_size;
  const float* x   = (const float*)d_in[0];
  const float* tw  = (const float*)d_in[3];
  const float* SN  = (const float*)d_in[4];
  const float* ctx = (const float*)d_in[5];
  const float* Wq  = (const float*)d_in[6];
  const float* bq  = (const float*)d_in[7];
  const float* Wk  = (const float*)d_in[8];
  const float* Wv  = (const float*)d_in[10];
  const float* bv  = (const float*)d_in[11];
  const float* pat = (const float*)d_in[12];
  const float* Wup = (const float*)d_in[13];
  const float* bup = (const float*)d_in[14];
  const float* Wdn = (const float*)d_in[15];
  const float* bdn = (const float*)d_in[16];
  float* out = (float*)d_out;

  char* ws = (char*)d_ws;
  size_t off = 0;
  auto alloc = [&](size_t bytes) -> char* {
    char* p = ws + off;
    off = (off + bytes + 255) & ~(size_t)255;
    return p;
  };
  ushort_t* SNB  = (ushort_t*)alloc(67108864);  // SN bf16 [32768][1024]; later aliased by H
  ushort_t* TB   = (ushort_t*)alloc(67108864);  // T bf16; later aliased by COMBINED
  float*    CBb  = (float*)alloc(524288);       // [4096][32]
  ushort_t* GSN  = (ushort_t*)alloc(8388608);   // [4096][1024] bf16
  ushort_t* CTXB = (ushort_t*)alloc(8388608);
  ushort_t* PATB = (ushort_t*)alloc(65536);
  ushort_t* WVB  = (ushort_t*)alloc(2097152);
  ushort_t* WUPB = (ushort_t*)alloc(8388608);
  ushort_t* WDNB = (ushort_t*)alloc(8388608);
  ushort_t* ATB  = (ushort_t*)alloc(2097152);
  ushort_t* WKTB = (ushort_t*)alloc(2097152);
  ushort_t* WQTB = (ushort_t*)alloc(2097152);
  ushort_t* WVTB = (ushort_t*)alloc(2097152);
  ushort_t* PVB  = (ushort_t*)alloc(65536);
  float*    WVEC = (float*)alloc(4096);
  float*    PBv  = (float*)alloc(128);
  ushort_t* H    = SNB;   // 32MB alias (SNB dead by FFN time)
  ushort_t* CMB  = TB;    // 8MB alias (T dead after k_attn)

  // launch 1: converts + weight transposes (independent tensors, one kernel)
  const int e0 = 8388608, e1 = e0 + 1048576, e2 = e1 + 8192,
            e3 = e2 + 262144, e4 = e3 + 1048576, e5 = e4 + 1048576;
  const int cvtb = (e5 + 255) / 256;
  k_cvt_tr<<<cvtb + 3072, 256, 0, stream>>>(
      SN, SNB, e0, ctx, CTXB, e1, pat, PATB, e2,
      Wv, WVB, e3, Wup, WUPB, e4, Wdn, WDNB, e5,
      Wq, WQTB, Wk, WKTB, Wv, WVTB, cvtb);
  // launch 2: prep (wvec|pb|PV|CB) + ATB GEMM (all inputs from launch 1)
  k_prep<<<680, 256, 0, stream>>>(bq, WKTB, WVEC, pat, bv, PBv, WVTB, PATB, PVB,
                                  CTXB, CBb, WQTB, ATB);

  // T = SN @ At^T + wvec   (256x256 4-phase; 128 m-tiles x 4 n-tiles = 512 blocks)
  k_gemm8<1><<<512, 512, 0, stream>>>(SNB, ATB, TB, WVEC, 1024, 1024, 4);
  // fused: logits+NPRE (MFMA) -> softmax/top-4/final_attn -> gsn
  k_attn<<<512, 256, 0, stream>>>(TB, SNB, PVB, PBv, CBb, tw, GSN);
  // combined = gsn @ Wv^T + bv + x   (bf16, 64x128 tiles, 512 blocks)
  k_gemm_bt64<2, 8><<<512, 256, 0, stream>>>(GSN, WVB, CMB, bv, x, 1024, 1024);
  // H = gelu(combined @ Wup^T + bup)  (256x256 4-phase; 16 m x 16 n = 256 blocks)
  k_gemm8<3><<<256, 512, 0, stream>>>(CMB, WUPB, H, bup, 4096, 1024, 16);
  // out = H @ Wdown^T + bdn  (fp32, 64x128 tiles, 512 blocks)
  k_gemm_bt64<4, 8><<<512, 256, 0, stream>>>(H, WDNB, out, bdn, nullptr, 1024, 4096);
}